// Round 3
// baseline (252.546 us; speedup 1.0000x reference)
//
#include <hip/hip_runtime.h>
#include <stdint.h>

#define Bx 8
#define Tx 2048
#define Sx 2048
#define Hx 64

typedef __attribute__((ext_vector_type(4))) float f32x4;
typedef __attribute__((ext_vector_type(8))) short short8;
typedef __attribute__((ext_vector_type(4))) unsigned short ushort4v;
typedef __attribute__((ext_vector_type(4))) unsigned int uint4v;

// fp32 -> bf16 round-to-nearest-even (finite inputs only)
__device__ __forceinline__ unsigned short f2b(float f) {
  unsigned int u = __builtin_bit_cast(unsigned int, f);
  u = (u + 0x7FFFu + ((u >> 16) & 1u)) >> 16;
  return (unsigned short)u;
}
__device__ __forceinline__ float b2f(unsigned short h) {
  unsigned int u = ((unsigned int)h) << 16;
  return __builtin_bit_cast(float, u);
}

// 8 fp32 -> (hi, lo) bf16x8: x ~= hi + lo (RNE hi + RNE residual) [R3/R5-proven]
__device__ __forceinline__ void cvt_hilo(f32x4 a, f32x4 b, short8& hi, short8& lo) {
  #pragma unroll
  for (int j = 0; j < 4; j++) {
    unsigned short h = f2b(a[j]);
    hi[j] = (short)h;
    lo[j] = (short)f2b(a[j] - b2f(h));
  }
  #pragma unroll
  for (int j = 0; j < 4; j++) {
    unsigned short h = f2b(b[j]);
    hi[4 + j] = (short)h;
    lo[4 + j] = (short)f2b(b[j] - b2f(h));
  }
}

// ---------------- prep kernels (fast path only) ----------------
// K (fp32 [B,S,64]) -> Khi, Klo (bf16, same layout); same numerics as cvt_hilo.
__global__ void __launch_bounds__(256) kprep_kernel(
    const float* __restrict__ K,
    unsigned short* __restrict__ Khi, unsigned short* __restrict__ Klo) {
  const size_t base = ((size_t)blockIdx.x * 256 + threadIdx.x) * 8;
  f32x4 a = *(const f32x4*)(K + base);
  f32x4 b = *(const f32x4*)(K + base + 4);
  ushort4v h0, h1, l0, l1;
  #pragma unroll
  for (int j = 0; j < 4; j++) {
    unsigned short h = f2b(a[j]);
    h0[j] = h; l0[j] = f2b(a[j] - b2f(h));
  }
  #pragma unroll
  for (int j = 0; j < 4; j++) {
    unsigned short h = f2b(b[j]);
    h1[j] = h; l1[j] = f2b(b[j] - b2f(h));
  }
  *(ushort4v*)(Khi + base) = h0;
  *(ushort4v*)(Khi + base + 4) = h1;
  *(ushort4v*)(Klo + base) = l0;
  *(ushort4v*)(Klo + base + 4) = l1;
}

// V (fp32 [B,S,64]) -> Vt (bf16 [B,64,S]) with per-32 s-permutation:
//   Vt[b][h][32*m + k] = V[b][32*m + s(k)][h],  s(k)=4*(k>>3)+(k&3)+16*((k>>2)&1)
// This makes the PV B-fragment's k-slice (k = q4*8+j) contiguous, matching the
// swapped-QK^T register layout of P (lane holds s = 4*q4+{0..3} and 16+4*q4+{0..3}).
__global__ void __launch_bounds__(256) vtrans_kernel(
    const float* __restrict__ V, unsigned short* __restrict__ Vt) {
  __shared__ __align__(16) unsigned short tile[64][72];
  const int b  = blockIdx.x >> 5;        // 8 * 32 blocks
  const int s0 = (blockIdx.x & 31) << 6;
  const float* Vb = V + ((size_t)b * Sx + s0) * Hx;
  unsigned short* Vo = Vt + (size_t)b * Hx * Sx;
  #pragma unroll
  for (int r = 0; r < 4; r++) {
    int flat = r * 1024 + threadIdx.x * 4;
    int sl = flat >> 6, h = flat & 63;
    f32x4 v = *(const f32x4*)(Vb + (size_t)sl * Hx + h);
    tile[h + 0][sl] = f2b(v[0]);
    tile[h + 1][sl] = f2b(v[1]);
    tile[h + 2][sl] = f2b(v[2]);
    tile[h + 3][sl] = f2b(v[3]);
  }
  __syncthreads();
  #pragma unroll
  for (int r = 0; r < 2; r++) {
    int u = r * 256 + threadIdx.x;
    int h = u >> 3, q = u & 7;
    int base = (q >> 2) * 32 + (q & 3) * 4;     // 32-block m = q>>2, q4 = q&3
    ushort4v lo4 = *(const ushort4v*)&tile[h][base];
    ushort4v hi4 = *(const ushort4v*)&tile[h][base + 16];
    short8 o;
    #pragma unroll
    for (int j = 0; j < 4; j++) {
      o[j]     = (short)lo4[j];
      o[4 + j] = (short)hi4[j];
    }
    *(short8*)(Vo + (size_t)h * Sx + s0 + q * 8) = o;
  }
}

// ---------------- fast attention (prepped K/V in d_ws) ----------------
// R3 restructure: 8 waves/block (256 s-values per wave), PV fused into pass A
// using UNNORMALIZED e (scale O by rl at the end), pass B = pure store stream.
// Rationale (R2 lesson): kernel is latency-bound on per-wave serial chains and
// on the store/load vmcnt coupling in the old pass B. No spill-risky bounds.
__global__ void __launch_bounds__(512) attn_fast_kernel(
    const float* __restrict__ Q, const int* __restrict__ mask,
    const unsigned short* __restrict__ Khi, const unsigned short* __restrict__ Klo,
    const unsigned short* __restrict__ Vt,
    float* __restrict__ Pg, float* __restrict__ Og) {
  const int tid  = threadIdx.x;
  const int lane = tid & 63;
  const int w    = tid >> 6;            // 0..7
  const int c16  = lane & 15;
  const int q4   = lane >> 4;
  const int b    = blockIdx.x & 7;      // XCD-affinity: batch <-> XCD
  const int t0   = (blockIdx.x >> 3) << 4;

  __shared__ float Lred[8][16];
  __shared__ float RL[16];
  __shared__ __align__(16) float Ored[8][16][68];

  const float* Qb = Q + ((size_t)b * Tx + t0) * Hx;
  const unsigned short* Khb = Khi + (size_t)b * Sx * Hx;
  const unsigned short* Klb = Klo + (size_t)b * Sx * Hx;
  const unsigned short* Vtb = Vt + (size_t)b * Hx * Sx;
  const int* Mb = mask + (size_t)b * Sx;

  // Q hi/lo B-fragments: B[k=q4*8+j][n=c16] (+32)
  short8 aQ0h, aQ0l, aQ1h, aQ1l;
  {
    const float* qp = Qb + c16 * Hx + q4 * 8;
    f32x4 qa = *(const f32x4*)qp;
    f32x4 qb = *(const f32x4*)(qp + 4);
    f32x4 qc = *(const f32x4*)(qp + 32);
    f32x4 qd = *(const f32x4*)(qp + 36);
    cvt_hilo(qa, qb, aQ0h, aQ0l);
    cvt_hilo(qc, qd, aQ1h, aQ1l);
  }

  const int sBeg = w * (Sx / 8);        // 256 s-values per wave

  // ---- pass A: scores -> e (cached in ppk) + fused PV on unnormalized e ----
  // Swapped operands: lane holds P[t0+c16][s0 + 4*q4 + r], r=0..3.
  unsigned int ppk[32];
  f32x4 oacc[4];
  #pragma unroll
  for (int f = 0; f < 4; f++) oacc[f] = (f32x4){0.f, 0.f, 0.f, 0.f};
  float ls = 0.f;

  #pragma unroll
  for (int ti = 0; ti < 16; ti++) {
    const int s0 = sBeg + ti * 16;
    const size_t off = (size_t)(s0 + c16) * Hx + q4 * 8;
    short8 k0h = *(const short8*)(Khb + off);
    short8 k1h = *(const short8*)(Khb + off + 32);
    short8 k0l = *(const short8*)(Klb + off);
    short8 k1l = *(const short8*)(Klb + off + 32);
    f32x4 d = {0.f, 0.f, 0.f, 0.f};
    d = __builtin_amdgcn_mfma_f32_16x16x32_bf16(k0h, aQ0h, d, 0, 0, 0);
    d = __builtin_amdgcn_mfma_f32_16x16x32_bf16(k1h, aQ1h, d, 0, 0, 0);
    d = __builtin_amdgcn_mfma_f32_16x16x32_bf16(k0l, aQ0h, d, 0, 0, 0);
    d = __builtin_amdgcn_mfma_f32_16x16x32_bf16(k1l, aQ1h, d, 0, 0, 0);
    d = __builtin_amdgcn_mfma_f32_16x16x32_bf16(k0h, aQ0l, d, 0, 0, 0);
    d = __builtin_amdgcn_mfma_f32_16x16x32_bf16(k1h, aQ1l, d, 0, 0, 0);
    const int4 mvv = *(const int4*)(Mb + s0 + q4 * 4);
    const int mv[4] = {mvv.x, mvv.y, mvv.z, mvv.w};
    float e[4];
    #pragma unroll
    for (int r = 0; r < 4; r++) {
      float x = mv[r] ? d[r] : -1e9f;
      x = fminf(x, 80.f);
      e[r] = __expf(x);
      ls += e[r];
    }
    ppk[ti * 2]     = (unsigned int)f2b(e[0]) | ((unsigned int)f2b(e[1]) << 16);
    ppk[ti * 2 + 1] = (unsigned int)f2b(e[2]) | ((unsigned int)f2b(e[3]) << 16);

    if (ti & 1) {
      // PV on the completed 32-block: A-fragment is the lane's own packed
      // bf16(e) words (permuted-Vt contract: k=q4*8+j <-> s=4*q4+(j&3)+16*(j>>2)).
      const int s0m = sBeg + (ti - 1) * 16;
      uint4v uv = { ppk[ti * 2 - 2], ppk[ti * 2 - 1],
                    ppk[ti * 2],     ppk[ti * 2 + 1] };
      short8 aP = __builtin_bit_cast(short8, uv);
      #pragma unroll
      for (int f = 0; f < 4; f++) {
        short8 bV = *(const short8*)(Vtb + (size_t)(f * 16 + c16) * Sx + s0m + q4 * 8);
        oacc[f] = __builtin_amdgcn_mfma_f32_16x16x32_bf16(aP, bV, oacc[f], 0, 0, 0);
      }
    }
  }

  // per-t row sum: reduce across the 4 q4-groups, then across 8 waves
  ls += __shfl_xor(ls, 16, 64);
  ls += __shfl_xor(ls, 32, 64);
  if (lane < 16) Lred[w][lane] = ls;
  __syncthreads();
  if (tid < 16) {
    float l = 0.f;
    #pragma unroll
    for (int ww = 0; ww < 8; ww++) l += Lred[ww][tid];
    RL[tid] = 1.0f / l;
  }
  __syncthreads();
  const float rlr = RL[c16];            // normalizer for P rows (t = c16)
  float rlv[4];
  #pragma unroll
  for (int r = 0; r < 4; r++) rlv[r] = RL[q4 * 4 + r];   // for O rows (t = q4*4+r)

  // ---------------- pass B: PURE normalized-P store stream ----------------
  float* Pb = Pg + ((size_t)b * Tx + t0) * Sx;
  #pragma unroll
  for (int it = 0; it < 8; it++) {
    const int s0 = sBeg + it * 32;
    const unsigned int a01 = ppk[it * 4 + 0];
    const unsigned int a23 = ppk[it * 4 + 1];
    const unsigned int b01 = ppk[it * 4 + 2];
    const unsigned int b23 = ppk[it * 4 + 3];
    f32x4 pA, pB;
    pA[0] = b2f((unsigned short)a01) * rlr;
    pA[1] = b2f((unsigned short)(a01 >> 16)) * rlr;
    pA[2] = b2f((unsigned short)a23) * rlr;
    pA[3] = b2f((unsigned short)(a23 >> 16)) * rlr;
    pB[0] = b2f((unsigned short)b01) * rlr;
    pB[1] = b2f((unsigned short)(b01 >> 16)) * rlr;
    pB[2] = b2f((unsigned short)b23) * rlr;
    pB[3] = b2f((unsigned short)(b23 >> 16)) * rlr;
    float* prow = Pb + (size_t)c16 * Sx + s0 + q4 * 4;
    *(f32x4*)prow        = pA;
    *(f32x4*)(prow + 16) = pB;
  }

  // ---- epilogue: scale O partials by rl, reduce across 8 waves, store ----
  #pragma unroll
  for (int f = 0; f < 4; f++) {
    #pragma unroll
    for (int r = 0; r < 4; r++) {
      Ored[w][q4 * 4 + r][f * 16 + c16] = oacc[f][r] * rlv[r];
    }
  }
  __syncthreads();
  if (tid < 256) {
    const int t  = tid >> 4;
    const int h4 = (tid & 15) * 4;
    f32x4 s = (f32x4){0.f, 0.f, 0.f, 0.f};
    #pragma unroll
    for (int ww = 0; ww < 8; ww++) {
      f32x4 a = *(const f32x4*)&Ored[ww][t][h4];
      #pragma unroll
      for (int j = 0; j < 4; j++) s[j] += a[j];
    }
    *(f32x4*)(Og + ((size_t)b * Tx + t0 + t) * Hx + h4) = s;
  }
}

// ---------------- slow attention (R5 verbatim, no scratch) ----------------
__device__ __forceinline__ f32x4 qk_tile(const float* __restrict__ kp,
    short8 aQ0h, short8 aQ0l, short8 aQ1h, short8 aQ1l) {
  f32x4 a0 = *(const f32x4*)(kp);
  f32x4 a1 = *(const f32x4*)(kp + 4);
  f32x4 b0 = *(const f32x4*)(kp + 32);
  f32x4 b1 = *(const f32x4*)(kp + 36);
  short8 k0h, k0l, k1h, k1l;
  cvt_hilo(a0, a1, k0h, k0l);
  cvt_hilo(b0, b1, k1h, k1l);
  f32x4 d = {0.f, 0.f, 0.f, 0.f};
  d = __builtin_amdgcn_mfma_f32_16x16x32_bf16(aQ0h, k0h, d, 0, 0, 0);
  d = __builtin_amdgcn_mfma_f32_16x16x32_bf16(aQ1h, k1h, d, 0, 0, 0);
  d = __builtin_amdgcn_mfma_f32_16x16x32_bf16(aQ0h, k0l, d, 0, 0, 0);
  d = __builtin_amdgcn_mfma_f32_16x16x32_bf16(aQ1h, k1l, d, 0, 0, 0);
  d = __builtin_amdgcn_mfma_f32_16x16x32_bf16(aQ0l, k0h, d, 0, 0, 0);
  d = __builtin_amdgcn_mfma_f32_16x16x32_bf16(aQ1l, k1h, d, 0, 0, 0);
  return d;
}

__global__ void __launch_bounds__(256) attn_kernel(
    const float* __restrict__ Q, const float* __restrict__ K,
    const float* __restrict__ V, const int* __restrict__ mask,
    float* __restrict__ Pg, float* __restrict__ Og) {
  const int tid  = threadIdx.x;
  const int lane = tid & 63;
  const int w    = tid >> 6;
  const int c16  = lane & 15;
  const int q4   = lane >> 4;
  const int b    = blockIdx.x & 7;
  const int t0   = (blockIdx.x >> 3) << 4;

  __shared__ __align__(16) unsigned short Vlds[4][64][40];
  __shared__ __align__(16) float Pf[4][16][36];
  __shared__ float Lred[4][16];
  __shared__ float RL[16];
  __shared__ __align__(16) float Ored[4][16][68];

  const float* Qb = Q + ((size_t)b * Tx + t0) * Hx;
  const float* Kb = K + (size_t)b * Sx * Hx;
  const float* Vb = V + (size_t)b * Sx * Hx;
  const int* Mb = mask + (size_t)b * Sx;

  short8 aQ0h, aQ0l, aQ1h, aQ1l;
  {
    const float* qp = Qb + c16 * Hx + q4 * 8;
    f32x4 qa = *(const f32x4*)qp;
    f32x4 qb = *(const f32x4*)(qp + 4);
    f32x4 qc = *(const f32x4*)(qp + 32);
    f32x4 qd = *(const f32x4*)(qp + 36);
    cvt_hilo(qa, qb, aQ0h, aQ0l);
    cvt_hilo(qc, qd, aQ1h, aQ1l);
  }

  const int sBeg = w * (Sx / 4);

  unsigned int ppk[64];
  float ls[4] = {0.f, 0.f, 0.f, 0.f};
  #pragma unroll
  for (int ti = 0; ti < 32; ti++) {
    const int s0 = sBeg + ti * 16;
    f32x4 d = qk_tile(Kb + (size_t)(s0 + c16) * Hx + q4 * 8,
                      aQ0h, aQ0l, aQ1h, aQ1l);
    const int mv = Mb[s0 + c16];
    float e[4];
    #pragma unroll
    for (int r = 0; r < 4; r++) {
      float x = mv ? d[r] : -1e9f;
      x = fminf(x, 80.f);
      e[r] = __expf(x);
      ls[r] += e[r];
    }
    ppk[ti * 2]     = (unsigned int)f2b(e[0]) | ((unsigned int)f2b(e[1]) << 16);
    ppk[ti * 2 + 1] = (unsigned int)f2b(e[2]) | ((unsigned int)f2b(e[3]) << 16);
  }
  #pragma unroll
  for (int r = 0; r < 4; r++) {
    float v = ls[r];
    v += __shfl_xor(v, 1, 64);
    v += __shfl_xor(v, 2, 64);
    v += __shfl_xor(v, 4, 64);
    v += __shfl_xor(v, 8, 64);
    if (c16 == 0) Lred[w][q4 * 4 + r] = v;
  }
  __syncthreads();
  if (tid < 16) {
    float l = Lred[0][tid] + Lred[1][tid] + Lred[2][tid] + Lred[3][tid];
    RL[tid] = 1.0f / l;
  }
  __syncthreads();

  float rl[4];
  #pragma unroll
  for (int r = 0; r < 4; r++) rl[r] = RL[q4 * 4 + r];

  f32x4 oacc[4];
  #pragma unroll
  for (int f = 0; f < 4; f++) oacc[f] = (f32x4){0.f, 0.f, 0.f, 0.f};

  float* Pb = Pg + ((size_t)b * Tx + t0) * Sx;

  #pragma unroll
  for (int it = 0; it < 16; it++) {
    const int s0 = sBeg + it * 32;
    #pragma unroll
    for (int vit = 0; vit < 8; vit++) {
      int chunk = vit * 64 + lane;
      int sl = chunk >> 4;
      int hq = chunk & 15;
      f32x4 vv = *(const f32x4*)(Vb + (size_t)(s0 + sl) * Hx + hq * 4);
      Vlds[w][hq * 4 + 0][sl] = f2b(vv[0]);
      Vlds[w][hq * 4 + 1][sl] = f2b(vv[1]);
      Vlds[w][hq * 4 + 2][sl] = f2b(vv[2]);
      Vlds[w][hq * 4 + 3][sl] = f2b(vv[3]);
    }
    #pragma unroll
    for (int sub = 0; sub < 2; sub++) {
      unsigned int a01 = ppk[it * 4 + sub * 2];
      unsigned int a23 = ppk[it * 4 + sub * 2 + 1];
      Pf[w][q4 * 4 + 0][sub * 16 + c16] = b2f((unsigned short)a01) * rl[0];
      Pf[w][q4 * 4 + 1][sub * 16 + c16] = b2f((unsigned short)(a01 >> 16)) * rl[1];
      Pf[w][q4 * 4 + 2][sub * 16 + c16] = b2f((unsigned short)a23) * rl[2];
      Pf[w][q4 * 4 + 3][sub * 16 + c16] = b2f((unsigned short)(a23 >> 16)) * rl[3];
    }
    __syncthreads();
    {
      const int row = lane >> 2;
      const int ch  = lane & 3;
      f32x4 v0 = *(const f32x4*)&Pf[w][row][ch * 4];
      f32x4 v1 = *(const f32x4*)&Pf[w][row][16 + ch * 4];
      *(f32x4*)(Pb + (size_t)row * Sx + s0 + ch * 4) = v0;
      *(f32x4*)(Pb + (size_t)row * Sx + s0 + 16 + ch * 4) = v1;
    }
    f32x4 pa = *(const f32x4*)&Pf[w][c16][q4 * 8];
    f32x4 pc = *(const f32x4*)&Pf[w][c16][q4 * 8 + 4];
    short8 aP;
    #pragma unroll
    for (int j = 0; j < 4; j++) {
      aP[j]     = (short)f2b(pa[j]);
      aP[4 + j] = (short)f2b(pc[j]);
    }
    #pragma unroll
    for (int f = 0; f < 4; f++) {
      short8 bV = *(const short8*)&Vlds[w][f * 16 + c16][q4 * 8];
      oacc[f] = __builtin_amdgcn_mfma_f32_16x16x32_bf16(aP, bV, oacc[f], 0, 0, 0);
    }
    __syncthreads();
  }

  #pragma unroll
  for (int f = 0; f < 4; f++) {
    #pragma unroll
    for (int r = 0; r < 4; r++) {
      Ored[w][q4 * 4 + r][f * 16 + c16] = oacc[f][r];
    }
  }
  __syncthreads();
  {
    const int t  = tid >> 4;
    const int h4 = (tid & 15) * 4;
    f32x4 a0 = *(const f32x4*)&Ored[0][t][h4];
    f32x4 a1 = *(const f32x4*)&Ored[1][t][h4];
    f32x4 a2 = *(const f32x4*)&Ored[2][t][h4];
    f32x4 a3 = *(const f32x4*)&Ored[3][t][h4];
    f32x4 o;
    #pragma unroll
    for (int j = 0; j < 4; j++) o[j] = a0[j] + a1[j] + a2[j] + a3[j];
    *(f32x4*)(Og + ((size_t)b * Tx + t0 + t) * Hx + h4) = o;
  }
}

extern "C" void kernel_launch(void* const* d_in, const int* in_sizes, int n_in,
                              void* d_out, int out_size, void* d_ws, size_t ws_size,
                              hipStream_t stream) {
  const float* Q = (const float*)d_in[0];
  const float* K = (const float*)d_in[1];
  const float* V = (const float*)d_in[2];
  const int* mask = (const int*)d_in[3];

  float* Og = (float*)d_out;                       // o_attn: 8*2048*64 fp32
  float* Pg = Og + (size_t)Bx * Tx * Hx;           // p_attn: 8*2048*2048 fp32

  const size_t nKV = (size_t)Bx * Sx * Hx;         // 1,048,576 elements
  if (ws_size >= nKV * 6) {                        // 6 MB needed for Khi/Klo/Vt
    unsigned short* Khi = (unsigned short*)d_ws;
    unsigned short* Klo = Khi + nKV;
    unsigned short* Vt  = Klo + nKV;
    kprep_kernel<<<dim3(512), dim3(256), 0, stream>>>(K, Khi, Klo);
    vtrans_kernel<<<dim3(Bx * (Sx / 64)), dim3(256), 0, stream>>>(V, Vt);
    attn_fast_kernel<<<dim3(Bx * (Tx / 16)), dim3(512), 0, stream>>>(
        Q, mask, Khi, Klo, Vt, Pg, Og);
  } else {
    attn_kernel<<<dim3(Bx * (Tx / 16)), dim3(256), 0, stream>>>(Q, K, V, mask, Pg, Og);
  }
}

// Round 4
// 183.367 us; speedup vs baseline: 1.3773x; 1.3773x over previous
//
#include <hip/hip_runtime.h>
#include <stdint.h>

#define Bx 8
#define Tx 2048
#define Sx 2048
#define Hx 64

typedef __attribute__((ext_vector_type(4))) float f32x4;
typedef __attribute__((ext_vector_type(8))) short short8;
typedef __attribute__((ext_vector_type(4))) unsigned short ushort4v;

// fp32 -> bf16 round-to-nearest-even (finite inputs only)
__device__ __forceinline__ unsigned short f2b(float f) {
  unsigned int u = __builtin_bit_cast(unsigned int, f);
  u = (u + 0x7FFFu + ((u >> 16) & 1u)) >> 16;
  return (unsigned short)u;
}
__device__ __forceinline__ float b2f(unsigned short h) {
  unsigned int u = ((unsigned int)h) << 16;
  return __builtin_bit_cast(float, u);
}

// 8 fp32 -> (hi, lo) bf16x8: x ~= hi + lo (RNE hi + RNE residual) [R3/R5-proven]
__device__ __forceinline__ void cvt_hilo(f32x4 a, f32x4 b, short8& hi, short8& lo) {
  #pragma unroll
  for (int j = 0; j < 4; j++) {
    unsigned short h = f2b(a[j]);
    hi[j] = (short)h;
    lo[j] = (short)f2b(a[j] - b2f(h));
  }
  #pragma unroll
  for (int j = 0; j < 4; j++) {
    unsigned short h = f2b(b[j]);
    hi[4 + j] = (short)h;
    lo[4 + j] = (short)f2b(b[j] - b2f(h));
  }
}

// ---------------- fused prep kernel (fast path only) ----------------
// Blocks 0..255:  K (fp32 [B,S,64]) -> Kf, MFMA-fragment order:
//   per 16-s tile t: 4 chunks [k0h|k1h|k0l|k1l], each 512 shorts lane-linear:
//   chunk[lane*8+j] = K{hi,lo}[tile*16 + (lane&15)][(lane>>4)*8 + j (+32 for k1)]
//   so the attn wave loads each chunk as ONE fully-coalesced 1KB dwordx4 load
//   (8 full 128B lines = 8 L2 requests, vs 16 partial-line requests before).
// Blocks 256..511: V (fp32 [B,S,64]) -> Vf, fragment order with the per-32
//   s-permutation s(k)=4*(k>>3)+(k&3)+16*((k>>2)&1) baked in (R1-proven):
//   per 32-s block m: 4 chunks (f=0..3) of 512 shorts lane-linear:
//   chunk_f[lane*8+j] = bf16(V[m*32 + 4*q4+(j&3)+16*(j>>2)][f*16 + c16])
__global__ void __launch_bounds__(256) prep_kernel(
    const float* __restrict__ K, const float* __restrict__ V,
    unsigned short* __restrict__ Kf, unsigned short* __restrict__ Vf) {
  const int bid = blockIdx.x;
  if (bid < 256) {
    const int b  = bid >> 5;              // 32 s-blocks of 64 per batch
    const int s0 = (bid & 31) << 6;
    __shared__ __align__(16) unsigned short hiT[64][68];
    __shared__ __align__(16) unsigned short loT[64][68];
    const float* Kb = K + ((size_t)b * Sx + s0) * Hx;
    #pragma unroll
    for (int r = 0; r < 2; r++) {
      int idx = r * 2048 + threadIdx.x * 8;    // element in 64x64 tile
      int sl = idx >> 6;
      int h0 = idx & 63;
      f32x4 a = *(const f32x4*)(Kb + (size_t)sl * Hx + h0);
      f32x4 c = *(const f32x4*)(Kb + (size_t)sl * Hx + h0 + 4);
      #pragma unroll
      for (int j = 0; j < 4; j++) {
        unsigned short h = f2b(a[j]);
        hiT[sl][h0 + j] = h;
        loT[sl][h0 + j] = f2b(a[j] - b2f(h));
      }
      #pragma unroll
      for (int j = 0; j < 4; j++) {
        unsigned short h = f2b(c[j]);
        hiT[sl][h0 + 4 + j] = h;
        loT[sl][h0 + 4 + j] = f2b(c[j] - b2f(h));
      }
    }
    __syncthreads();
    unsigned short* out = Kf + ((size_t)b * 128 + (s0 >> 4)) * 2048;
    #pragma unroll
    for (int r = 0; r < 4; r++) {
      int id   = r * 256 + threadIdx.x;   // 0..1023 chunk-writes
      int tl   = id >> 8;                 // local tile 0..3
      int kind = (id >> 6) & 3;           // 0:k0h 1:k1h 2:k0l 3:k1l
      int lane = id & 63;
      int c16 = lane & 15, q4 = lane >> 4;
      int row = tl * 16 + c16;
      int col = q4 * 8 + (kind & 1) * 32;
      ushort4v x0, x1;
      if (kind & 2) {
        x0 = *(const ushort4v*)&loT[row][col];
        x1 = *(const ushort4v*)&loT[row][col + 4];
      } else {
        x0 = *(const ushort4v*)&hiT[row][col];
        x1 = *(const ushort4v*)&hiT[row][col + 4];
      }
      unsigned short* dst = out + ((size_t)tl * 4 + kind) * 512 + lane * 8;
      *(ushort4v*)dst = x0;
      *(ushort4v*)(dst + 4) = x1;
    }
  } else {
    const int vb = bid - 256;
    const int b  = vb >> 5;
    const int s0 = (vb & 31) << 6;
    __shared__ __align__(16) unsigned short tile[64][72];   // [h][s_local]
    const float* Vb = V + ((size_t)b * Sx + s0) * Hx;
    #pragma unroll
    for (int r = 0; r < 4; r++) {
      int flat = r * 1024 + threadIdx.x * 4;
      int sl = flat >> 6, h = flat & 63;
      f32x4 v = *(const f32x4*)(Vb + (size_t)sl * Hx + h);
      tile[h + 0][sl] = f2b(v[0]);
      tile[h + 1][sl] = f2b(v[1]);
      tile[h + 2][sl] = f2b(v[2]);
      tile[h + 3][sl] = f2b(v[3]);
    }
    __syncthreads();
    unsigned short* out = Vf + ((size_t)b * 64 + (s0 >> 5)) * 2048;
    #pragma unroll
    for (int r = 0; r < 2; r++) {
      int id   = r * 256 + threadIdx.x;   // 0..511 chunk-writes
      int ml   = id >> 8;                 // local 32-s block 0..1
      int f    = (id >> 6) & 3;
      int lane = id & 63;
      int c16 = lane & 15, q4 = lane >> 4;
      int h = f * 16 + c16;
      int sb = ml * 32 + q4 * 4;
      ushort4v lo4 = *(const ushort4v*)&tile[h][sb];        // j=0..3: s'=4q4+j
      ushort4v hi4 = *(const ushort4v*)&tile[h][sb + 16];   // j=4..7: s'=16+4q4+(j-4)
      short8 o;
      #pragma unroll
      for (int j = 0; j < 4; j++) {
        o[j]     = (short)lo4[j];
        o[4 + j] = (short)hi4[j];
      }
      *(short8*)(out + ((size_t)ml * 4 + f) * 512 + lane * 8) = o;
    }
  }
}

// ---------------- fast attention (fragment-packed K/V in d_ws) ----------------
// R2 structure (two-pass, 4 waves, barrier-free pass B) with fragment-order
// loads: every K/V load is a fully-coalesced 1KB dwordx4 (8 full-line L2
// requests vs 16 partial-line). R3 lesson: kernel is L2-request-rate bound.
__global__ void __launch_bounds__(256) attn_fast_kernel(
    const float* __restrict__ Q, const int* __restrict__ mask,
    const unsigned short* __restrict__ Kf, const unsigned short* __restrict__ Vf,
    float* __restrict__ Pg, float* __restrict__ Og) {
  const int tid  = threadIdx.x;
  const int lane = tid & 63;
  const int w    = tid >> 6;
  const int c16  = lane & 15;
  const int q4   = lane >> 4;
  const int b    = blockIdx.x & 7;          // XCD-affinity: batch <-> XCD
  const int t0   = (blockIdx.x >> 3) << 4;

  __shared__ float Lred[4][16];
  __shared__ __align__(16) float Ored[4][16][68];

  const float* Qb = Q + ((size_t)b * Tx + t0) * Hx;
  const unsigned short* Kfb = Kf + (size_t)b * 128 * 2048;
  const unsigned short* Vfb = Vf + (size_t)b * 64 * 2048;
  const int* Mb = mask + (size_t)b * Sx;

  // Q hi/lo fragments: [k=q4*8+j][n=c16] (+32)
  short8 aQ0h, aQ0l, aQ1h, aQ1l;
  {
    const float* qp = Qb + c16 * Hx + q4 * 8;
    f32x4 qa = *(const f32x4*)qp;
    f32x4 qb = *(const f32x4*)(qp + 4);
    f32x4 qc = *(const f32x4*)(qp + 32);
    f32x4 qd = *(const f32x4*)(qp + 36);
    cvt_hilo(qa, qb, aQ0h, aQ0l);
    cvt_hilo(qc, qd, aQ1h, aQ1l);
  }

  const int sBeg = w * (Sx / 4);            // 512 s per wave

  // ---------------- pass A: l = sum exp(score), e cached in ppk ----------
  // Swapped operands: lane holds P[t0+c16][s0 + 4*q4 + r], r=0..3.
  unsigned int ppk[64];
  float ls = 0.f;
  #pragma unroll
  for (int ti = 0; ti < 32; ti++) {
    const int s0 = sBeg + ti * 16;
    const unsigned short* kb = Kfb + (size_t)(w * 32 + ti) * 2048 + lane * 8;
    short8 k0h = *(const short8*)(kb);
    short8 k1h = *(const short8*)(kb + 512);
    short8 k0l = *(const short8*)(kb + 1024);
    short8 k1l = *(const short8*)(kb + 1536);
    f32x4 d = {0.f, 0.f, 0.f, 0.f};
    d = __builtin_amdgcn_mfma_f32_16x16x32_bf16(k0h, aQ0h, d, 0, 0, 0);
    d = __builtin_amdgcn_mfma_f32_16x16x32_bf16(k1h, aQ1h, d, 0, 0, 0);
    d = __builtin_amdgcn_mfma_f32_16x16x32_bf16(k0l, aQ0h, d, 0, 0, 0);
    d = __builtin_amdgcn_mfma_f32_16x16x32_bf16(k1l, aQ1h, d, 0, 0, 0);
    d = __builtin_amdgcn_mfma_f32_16x16x32_bf16(k0h, aQ0l, d, 0, 0, 0);
    d = __builtin_amdgcn_mfma_f32_16x16x32_bf16(k1h, aQ1l, d, 0, 0, 0);
    const int4 mvv = *(const int4*)(Mb + s0 + q4 * 4);
    const int mv[4] = {mvv.x, mvv.y, mvv.z, mvv.w};
    float e[4];
    #pragma unroll
    for (int r = 0; r < 4; r++) {
      float x = mv[r] ? d[r] : -1e9f;
      x = fminf(x, 80.f);
      e[r] = __expf(x);
      ls += e[r];
    }
    ppk[ti * 2]     = (unsigned int)f2b(e[0]) | ((unsigned int)f2b(e[1]) << 16);
    ppk[ti * 2 + 1] = (unsigned int)f2b(e[2]) | ((unsigned int)f2b(e[3]) << 16);
  }
  // per-t row sum: reduce across the 4 q4-groups (lanes c16, +16, +32, +48)
  ls += __shfl_xor(ls, 16, 64);
  ls += __shfl_xor(ls, 32, 64);
  if (lane < 16) Lred[w][lane] = ls;
  __syncthreads();
  const float rl = 1.0f / (Lred[0][c16] + Lred[1][c16] + Lred[2][c16] + Lred[3][c16]);

  // ---------------- pass B: direct P store + PV, no LDS, no barriers ------
  f32x4 oacc[4];
  #pragma unroll
  for (int f = 0; f < 4; f++) oacc[f] = (f32x4){0.f, 0.f, 0.f, 0.f};

  float* Pb = Pg + ((size_t)b * Tx + t0) * Sx;

  #pragma unroll
  for (int it = 0; it < 16; it++) {
    const int s0 = sBeg + it * 32;
    const unsigned int a01 = ppk[it * 4 + 0];
    const unsigned int a23 = ppk[it * 4 + 1];
    const unsigned int b01 = ppk[it * 4 + 2];
    const unsigned int b23 = ppk[it * 4 + 3];
    f32x4 pA, pB;
    pA[0] = b2f((unsigned short)a01) * rl;
    pA[1] = b2f((unsigned short)(a01 >> 16)) * rl;
    pA[2] = b2f((unsigned short)a23) * rl;
    pA[3] = b2f((unsigned short)(a23 >> 16)) * rl;
    pB[0] = b2f((unsigned short)b01) * rl;
    pB[1] = b2f((unsigned short)(b01 >> 16)) * rl;
    pB[2] = b2f((unsigned short)b23) * rl;
    pB[3] = b2f((unsigned short)(b23 >> 16)) * rl;

    // P store straight from registers: row t0+c16, 4+4 contiguous floats.
    float* prow = Pb + (size_t)c16 * Sx + s0 + q4 * 4;
    *(f32x4*)prow        = pA;
    *(f32x4*)(prow + 16) = pB;

    // PV: A-fragment from normalized e (permuted-Vf contract:
    //   k=q4*8+j <-> s = s0 + 4*q4 + (j&3) + 16*(j>>2));
    // B-fragment: one coalesced 1KB chunk per f.
    short8 aP;
    #pragma unroll
    for (int j = 0; j < 4; j++) {
      aP[j]     = (short)f2b(pA[j]);
      aP[4 + j] = (short)f2b(pB[j]);
    }
    const unsigned short* vb = Vfb + (size_t)(w * 16 + it) * 2048 + lane * 8;
    #pragma unroll
    for (int f = 0; f < 4; f++) {
      short8 bV = *(const short8*)(vb + f * 512);
      oacc[f] = __builtin_amdgcn_mfma_f32_16x16x32_bf16(aP, bV, oacc[f], 0, 0, 0);
    }
  }

  // PV output: lane holds O[t0 + q4*4 + r][f*16 + c16] (partial over wave's s).
  #pragma unroll
  for (int f = 0; f < 4; f++) {
    #pragma unroll
    for (int r = 0; r < 4; r++) {
      Ored[w][q4 * 4 + r][f * 16 + c16] = oacc[f][r];
    }
  }
  __syncthreads();
  {
    const int t  = tid >> 4;
    const int h4 = (tid & 15) * 4;
    f32x4 a0 = *(const f32x4*)&Ored[0][t][h4];
    f32x4 a1 = *(const f32x4*)&Ored[1][t][h4];
    f32x4 a2 = *(const f32x4*)&Ored[2][t][h4];
    f32x4 a3 = *(const f32x4*)&Ored[3][t][h4];
    f32x4 o;
    #pragma unroll
    for (int j = 0; j < 4; j++) o[j] = a0[j] + a1[j] + a2[j] + a3[j];
    *(f32x4*)(Og + ((size_t)b * Tx + t0 + t) * Hx + h4) = o;
  }
}

// ---------------- slow attention (no-workspace fallback, verbatim) ----------------
__device__ __forceinline__ f32x4 qk_tile(const float* __restrict__ kp,
    short8 aQ0h, short8 aQ0l, short8 aQ1h, short8 aQ1l) {
  f32x4 a0 = *(const f32x4*)(kp);
  f32x4 a1 = *(const f32x4*)(kp + 4);
  f32x4 b0 = *(const f32x4*)(kp + 32);
  f32x4 b1 = *(const f32x4*)(kp + 36);
  short8 k0h, k0l, k1h, k1l;
  cvt_hilo(a0, a1, k0h, k0l);
  cvt_hilo(b0, b1, k1h, k1l);
  f32x4 d = {0.f, 0.f, 0.f, 0.f};
  d = __builtin_amdgcn_mfma_f32_16x16x32_bf16(aQ0h, k0h, d, 0, 0, 0);
  d = __builtin_amdgcn_mfma_f32_16x16x32_bf16(aQ1h, k1h, d, 0, 0, 0);
  d = __builtin_amdgcn_mfma_f32_16x16x32_bf16(aQ0h, k0l, d, 0, 0, 0);
  d = __builtin_amdgcn_mfma_f32_16x16x32_bf16(aQ1h, k1l, d, 0, 0, 0);
  d = __builtin_amdgcn_mfma_f32_16x16x32_bf16(aQ0l, k0h, d, 0, 0, 0);
  d = __builtin_amdgcn_mfma_f32_16x16x32_bf16(aQ1l, k1h, d, 0, 0, 0);
  return d;
}

__global__ void __launch_bounds__(256) attn_kernel(
    const float* __restrict__ Q, const float* __restrict__ K,
    const float* __restrict__ V, const int* __restrict__ mask,
    float* __restrict__ Pg, float* __restrict__ Og) {
  const int tid  = threadIdx.x;
  const int lane = tid & 63;
  const int w    = tid >> 6;
  const int c16  = lane & 15;
  const int q4   = lane >> 4;
  const int b    = blockIdx.x & 7;
  const int t0   = (blockIdx.x >> 3) << 4;

  __shared__ __align__(16) unsigned short Vlds[4][64][40];
  __shared__ __align__(16) float Pf[4][16][36];
  __shared__ float Lred[4][16];
  __shared__ float RL[16];
  __shared__ __align__(16) float Ored[4][16][68];

  const float* Qb = Q + ((size_t)b * Tx + t0) * Hx;
  const float* Kb = K + (size_t)b * Sx * Hx;
  const float* Vb = V + (size_t)b * Sx * Hx;
  const int* Mb = mask + (size_t)b * Sx;

  short8 aQ0h, aQ0l, aQ1h, aQ1l;
  {
    const float* qp = Qb + c16 * Hx + q4 * 8;
    f32x4 qa = *(const f32x4*)qp;
    f32x4 qb = *(const f32x4*)(qp + 4);
    f32x4 qc = *(const f32x4*)(qp + 32);
    f32x4 qd = *(const f32x4*)(qp + 36);
    cvt_hilo(qa, qb, aQ0h, aQ0l);
    cvt_hilo(qc, qd, aQ1h, aQ1l);
  }

  const int sBeg = w * (Sx / 4);

  unsigned int ppk[64];
  float ls[4] = {0.f, 0.f, 0.f, 0.f};
  #pragma unroll
  for (int ti = 0; ti < 32; ti++) {
    const int s0 = sBeg + ti * 16;
    f32x4 d = qk_tile(Kb + (size_t)(s0 + c16) * Hx + q4 * 8,
                      aQ0h, aQ0l, aQ1h, aQ1l);
    const int mv = Mb[s0 + c16];
    float e[4];
    #pragma unroll
    for (int r = 0; r < 4; r++) {
      float x = mv ? d[r] : -1e9f;
      x = fminf(x, 80.f);
      e[r] = __expf(x);
      ls[r] += e[r];
    }
    ppk[ti * 2]     = (unsigned int)f2b(e[0]) | ((unsigned int)f2b(e[1]) << 16);
    ppk[ti * 2 + 1] = (unsigned int)f2b(e[2]) | ((unsigned int)f2b(e[3]) << 16);
  }
  #pragma unroll
  for (int r = 0; r < 4; r++) {
    float v = ls[r];
    v += __shfl_xor(v, 1, 64);
    v += __shfl_xor(v, 2, 64);
    v += __shfl_xor(v, 4, 64);
    v += __shfl_xor(v, 8, 64);
    if (c16 == 0) Lred[w][q4 * 4 + r] = v;
  }
  __syncthreads();
  if (tid < 16) {
    float l = Lred[0][tid] + Lred[1][tid] + Lred[2][tid] + Lred[3][tid];
    RL[tid] = 1.0f / l;
  }
  __syncthreads();

  float rl[4];
  #pragma unroll
  for (int r = 0; r < 4; r++) rl[r] = RL[q4 * 4 + r];

  f32x4 oacc[4];
  #pragma unroll
  for (int f = 0; f < 4; f++) oacc[f] = (f32x4){0.f, 0.f, 0.f, 0.f};

  float* Pb = Pg + ((size_t)b * Tx + t0) * Sx;

  #pragma unroll
  for (int it = 0; it < 16; it++) {
    const int s0 = sBeg + it * 32;
    #pragma unroll
    for (int vit = 0; vit < 8; vit++) {
      int chunk = vit * 64 + lane;
      int sl = chunk >> 4;
      int hq = chunk & 15;
      f32x4 vv = *(const f32x4*)(Vb + (size_t)(s0 + sl) * Hx + hq * 4);
      Vlds[w][hq * 4 + 0][sl] = f2b(vv[0]);
      Vlds[w][hq * 4 + 1][sl] = f2b(vv[1]);
      Vlds[w][hq * 4 + 2][sl] = f2b(vv[2]);
      Vlds[w][hq * 4 + 3][sl] = f2b(vv[3]);
    }
    #pragma unroll
    for (int sub = 0; sub < 2; sub++) {
      unsigned int a01 = ppk[it * 4 + sub * 2];
      unsigned int a23 = ppk[it * 4 + sub * 2 + 1];
      Pf[w][q4 * 4 + 0][sub * 16 + c16] = b2f((unsigned short)a01) * rl[0];
      Pf[w][q4 * 4 + 1][sub * 16 + c16] = b2f((unsigned short)(a01 >> 16)) * rl[1];
      Pf[w][q4 * 4 + 2][sub * 16 + c16] = b2f((unsigned short)a23) * rl[2];
      Pf[w][q4 * 4 + 3][sub * 16 + c16] = b2f((unsigned short)(a23 >> 16)) * rl[3];
    }
    __syncthreads();
    {
      const int row = lane >> 2;
      const int ch  = lane & 3;
      f32x4 v0 = *(const f32x4*)&Pf[w][row][ch * 4];
      f32x4 v1 = *(const f32x4*)&Pf[w][row][16 + ch * 4];
      *(f32x4*)(Pb + (size_t)row * Sx + s0 + ch * 4) = v0;
      *(f32x4*)(Pb + (size_t)row * Sx + s0 + 16 + ch * 4) = v1;
    }
    f32x4 pa = *(const f32x4*)&Pf[w][c16][q4 * 8];
    f32x4 pc = *(const f32x4*)&Pf[w][c16][q4 * 8 + 4];
    short8 aP;
    #pragma unroll
    for (int j = 0; j < 4; j++) {
      aP[j]     = (short)f2b(pa[j]);
      aP[4 + j] = (short)f2b(pc[j]);
    }
    #pragma unroll
    for (int f = 0; f < 4; f++) {
      short8 bV = *(const short8*)&Vlds[w][f * 16 + c16][q4 * 8];
      oacc[f] = __builtin_amdgcn_mfma_f32_16x16x32_bf16(aP, bV, oacc[f], 0, 0, 0);
    }
    __syncthreads();
  }

  #pragma unroll
  for (int f = 0; f < 4; f++) {
    #pragma unroll
    for (int r = 0; r < 4; r++) {
      Ored[w][q4 * 4 + r][f * 16 + c16] = oacc[f][r];
    }
  }
  __syncthreads();
  {
    const int t  = tid >> 4;
    const int h4 = (tid & 15) * 4;
    f32x4 a0 = *(const f32x4*)&Ored[0][t][h4];
    f32x4 a1 = *(const f32x4*)&Ored[1][t][h4];
    f32x4 a2 = *(const f32x4*)&Ored[2][t][h4];
    f32x4 a3 = *(const f32x4*)&Ored[3][t][h4];
    f32x4 o;
    #pragma unroll
    for (int j = 0; j < 4; j++) o[j] = a0[j] + a1[j] + a2[j] + a3[j];
    *(f32x4*)(Og + ((size_t)b * Tx + t0 + t) * Hx + h4) = o;
  }
}

extern "C" void kernel_launch(void* const* d_in, const int* in_sizes, int n_in,
                              void* d_out, int out_size, void* d_ws, size_t ws_size,
                              hipStream_t stream) {
  const float* Q = (const float*)d_in[0];
  const float* K = (const float*)d_in[1];
  const float* V = (const float*)d_in[2];
  const int* mask = (const int*)d_in[3];

  float* Og = (float*)d_out;                       // o_attn: 8*2048*64 fp32
  float* Pg = Og + (size_t)Bx * Tx * Hx;           // p_attn: 8*2048*2048 fp32

  const size_t nKV = (size_t)Bx * Sx * Hx;         // 1,048,576 elements
  if (ws_size >= nKV * 6) {                        // 6 MB: Kf (4MB) + Vf (2MB)
    unsigned short* Kf = (unsigned short*)d_ws;    // hi+lo fragment-packed
    unsigned short* Vf = Kf + nKV * 2;             // fragment-packed, permuted
    prep_kernel<<<dim3(512), dim3(256), 0, stream>>>(K, V, Kf, Vf);
    attn_fast_kernel<<<dim3(Bx * (Tx / 16)), dim3(256), 0, stream>>>(
        Q, mask, Kf, Vf, Pg, Og);
  } else {
    attn_kernel<<<dim3(Bx * (Tx / 16)), dim3(256), 0, stream>>>(Q, K, V, mask, Pg, Og);
  }
}

// Round 5
// 173.423 us; speedup vs baseline: 1.4562x; 1.0573x over previous
//
#include <hip/hip_runtime.h>
#include <stdint.h>

#define Bx 8
#define Tx 2048
#define Sx 2048
#define Hx 64

typedef __attribute__((ext_vector_type(4))) float f32x4;
typedef __attribute__((ext_vector_type(8))) short short8;
typedef __attribute__((ext_vector_type(4))) unsigned short ushort4v;

// fp32 -> bf16 round-to-nearest-even (finite inputs only)
__device__ __forceinline__ unsigned short f2b(float f) {
  unsigned int u = __builtin_bit_cast(unsigned int, f);
  u = (u + 0x7FFFu + ((u >> 16) & 1u)) >> 16;
  return (unsigned short)u;
}
__device__ __forceinline__ float b2f(unsigned short h) {
  unsigned int u = ((unsigned int)h) << 16;
  return __builtin_bit_cast(float, u);
}

// 8 fp32 -> (hi, lo) bf16x8: x ~= hi + lo (RNE hi + RNE residual) [R3/R5-proven]
__device__ __forceinline__ void cvt_hilo(f32x4 a, f32x4 b, short8& hi, short8& lo) {
  #pragma unroll
  for (int j = 0; j < 4; j++) {
    unsigned short h = f2b(a[j]);
    hi[j] = (short)h;
    lo[j] = (short)f2b(a[j] - b2f(h));
  }
  #pragma unroll
  for (int j = 0; j < 4; j++) {
    unsigned short h = f2b(b[j]);
    hi[4 + j] = (short)h;
    lo[4 + j] = (short)f2b(b[j] - b2f(h));
  }
}

// ---------------- fused prep kernel (fast path only) ----------------
// Blocks 0..255:  K (fp32 [B,S,64]) -> Kf, MFMA-fragment order:
//   per 16-s tile t: 4 chunks [k0h|k1h|k0l|k1l], each 512 shorts lane-linear:
//   chunk[lane*8+j] = K{hi,lo}[tile*16 + (lane&15)][(lane>>4)*8 + j (+32 for k1)]
//   so the attn wave loads each chunk as ONE fully-coalesced 1KB dwordx4 load
//   (8 full 128B lines = 8 L2 requests, vs 16 partial-line requests before).
// Blocks 256..511: V (fp32 [B,S,64]) -> Vf, fragment order with the per-32
//   s-permutation s(k)=4*(k>>3)+(k&3)+16*((k>>2)&1) baked in (R1-proven):
//   per 32-s block m: 4 chunks (f=0..3) of 512 shorts lane-linear:
//   chunk_f[lane*8+j] = bf16(V[m*32 + 4*q4+(j&3)+16*(j>>2)][f*16 + c16])
__global__ void __launch_bounds__(256) prep_kernel(
    const float* __restrict__ K, const float* __restrict__ V,
    unsigned short* __restrict__ Kf, unsigned short* __restrict__ Vf) {
  const int bid = blockIdx.x;
  if (bid < 256) {
    const int b  = bid >> 5;              // 32 s-blocks of 64 per batch
    const int s0 = (bid & 31) << 6;
    __shared__ __align__(16) unsigned short hiT[64][68];
    __shared__ __align__(16) unsigned short loT[64][68];
    const float* Kb = K + ((size_t)b * Sx + s0) * Hx;
    #pragma unroll
    for (int r = 0; r < 2; r++) {
      int idx = r * 2048 + threadIdx.x * 8;    // element in 64x64 tile
      int sl = idx >> 6;
      int h0 = idx & 63;
      f32x4 a = *(const f32x4*)(Kb + (size_t)sl * Hx + h0);
      f32x4 c = *(const f32x4*)(Kb + (size_t)sl * Hx + h0 + 4);
      #pragma unroll
      for (int j = 0; j < 4; j++) {
        unsigned short h = f2b(a[j]);
        hiT[sl][h0 + j] = h;
        loT[sl][h0 + j] = f2b(a[j] - b2f(h));
      }
      #pragma unroll
      for (int j = 0; j < 4; j++) {
        unsigned short h = f2b(c[j]);
        hiT[sl][h0 + 4 + j] = h;
        loT[sl][h0 + 4 + j] = f2b(c[j] - b2f(h));
      }
    }
    __syncthreads();
    unsigned short* out = Kf + ((size_t)b * 128 + (s0 >> 4)) * 2048;
    #pragma unroll
    for (int r = 0; r < 4; r++) {
      int id   = r * 256 + threadIdx.x;   // 0..1023 chunk-writes
      int tl   = id >> 8;                 // local tile 0..3
      int kind = (id >> 6) & 3;           // 0:k0h 1:k1h 2:k0l 3:k1l
      int lane = id & 63;
      int c16 = lane & 15, q4 = lane >> 4;
      int row = tl * 16 + c16;
      int col = q4 * 8 + (kind & 1) * 32;
      ushort4v x0, x1;
      if (kind & 2) {
        x0 = *(const ushort4v*)&loT[row][col];
        x1 = *(const ushort4v*)&loT[row][col + 4];
      } else {
        x0 = *(const ushort4v*)&hiT[row][col];
        x1 = *(const ushort4v*)&hiT[row][col + 4];
      }
      unsigned short* dst = out + ((size_t)tl * 4 + kind) * 512 + lane * 8;
      *(ushort4v*)dst = x0;
      *(ushort4v*)(dst + 4) = x1;
    }
  } else {
    const int vb = bid - 256;
    const int b  = vb >> 5;
    const int s0 = (vb & 31) << 6;
    __shared__ __align__(16) unsigned short tile[64][72];   // [h][s_local]
    const float* Vb = V + ((size_t)b * Sx + s0) * Hx;
    #pragma unroll
    for (int r = 0; r < 4; r++) {
      int flat = r * 1024 + threadIdx.x * 4;
      int sl = flat >> 6, h = flat & 63;
      f32x4 v = *(const f32x4*)(Vb + (size_t)sl * Hx + h);
      tile[h + 0][sl] = f2b(v[0]);
      tile[h + 1][sl] = f2b(v[1]);
      tile[h + 2][sl] = f2b(v[2]);
      tile[h + 3][sl] = f2b(v[3]);
    }
    __syncthreads();
    unsigned short* out = Vf + ((size_t)b * 64 + (s0 >> 5)) * 2048;
    #pragma unroll
    for (int r = 0; r < 2; r++) {
      int id   = r * 256 + threadIdx.x;   // 0..511 chunk-writes
      int ml   = id >> 8;                 // local 32-s block 0..1
      int f    = (id >> 6) & 3;
      int lane = id & 63;
      int c16 = lane & 15, q4 = lane >> 4;
      int h = f * 16 + c16;
      int sb = ml * 32 + q4 * 4;
      ushort4v lo4 = *(const ushort4v*)&tile[h][sb];        // j=0..3: s'=4q4+j
      ushort4v hi4 = *(const ushort4v*)&tile[h][sb + 16];   // j=4..7: s'=16+4q4+(j-4)
      short8 o;
      #pragma unroll
      for (int j = 0; j < 4; j++) {
        o[j]     = (short)lo4[j];
        o[4 + j] = (short)hi4[j];
      }
      *(short8*)(out + ((size_t)ml * 4 + f) * 512 + lane * 8) = o;
    }
  }
}

// ---------------- fast attention (fragment-packed K/V in d_ws) ----------------
// R4 structure + full-line P stores: each 16x32 P tile is staged through a
// wave-local LDS buffer (double-buffered by iteration parity, no cross-wave
// sync) and re-read so 8 lanes cover one row -> every store instruction
// writes 8 FULL 128B lines (8 L2 write requests vs 16 half-line before).
__global__ void __launch_bounds__(256) attn_fast_kernel(
    const float* __restrict__ Q, const int* __restrict__ mask,
    const unsigned short* __restrict__ Kf, const unsigned short* __restrict__ Vf,
    float* __restrict__ Pg, float* __restrict__ Og) {
  const int tid  = threadIdx.x;
  const int lane = tid & 63;
  const int w    = tid >> 6;
  const int c16  = lane & 15;
  const int q4   = lane >> 4;
  const int b    = blockIdx.x & 7;          // XCD-affinity: batch <-> XCD
  const int t0   = (blockIdx.x >> 3) << 4;

  __shared__ float Lred[4][16];
  __shared__ __align__(16) float Ored[4][16][68];
  __shared__ __align__(16) float Pst[4][2][16][36];   // wave-local P staging

  const float* Qb = Q + ((size_t)b * Tx + t0) * Hx;
  const unsigned short* Kfb = Kf + (size_t)b * 128 * 2048;
  const unsigned short* Vfb = Vf + (size_t)b * 64 * 2048;
  const int* Mb = mask + (size_t)b * Sx;

  // Q hi/lo fragments: [k=q4*8+j][n=c16] (+32)
  short8 aQ0h, aQ0l, aQ1h, aQ1l;
  {
    const float* qp = Qb + c16 * Hx + q4 * 8;
    f32x4 qa = *(const f32x4*)qp;
    f32x4 qb = *(const f32x4*)(qp + 4);
    f32x4 qc = *(const f32x4*)(qp + 32);
    f32x4 qd = *(const f32x4*)(qp + 36);
    cvt_hilo(qa, qb, aQ0h, aQ0l);
    cvt_hilo(qc, qd, aQ1h, aQ1l);
  }

  const int sBeg = w * (Sx / 4);            // 512 s per wave

  // ---------------- pass A: l = sum exp(score), e cached in ppk ----------
  // Swapped operands: lane holds P[t0+c16][s0 + 4*q4 + r], r=0..3.
  unsigned int ppk[64];
  float ls = 0.f;
  #pragma unroll
  for (int ti = 0; ti < 32; ti++) {
    const int s0 = sBeg + ti * 16;
    const unsigned short* kb = Kfb + (size_t)(w * 32 + ti) * 2048 + lane * 8;
    short8 k0h = *(const short8*)(kb);
    short8 k1h = *(const short8*)(kb + 512);
    short8 k0l = *(const short8*)(kb + 1024);
    short8 k1l = *(const short8*)(kb + 1536);
    f32x4 d = {0.f, 0.f, 0.f, 0.f};
    d = __builtin_amdgcn_mfma_f32_16x16x32_bf16(k0h, aQ0h, d, 0, 0, 0);
    d = __builtin_amdgcn_mfma_f32_16x16x32_bf16(k1h, aQ1h, d, 0, 0, 0);
    d = __builtin_amdgcn_mfma_f32_16x16x32_bf16(k0l, aQ0h, d, 0, 0, 0);
    d = __builtin_amdgcn_mfma_f32_16x16x32_bf16(k1l, aQ1h, d, 0, 0, 0);
    d = __builtin_amdgcn_mfma_f32_16x16x32_bf16(k0h, aQ0l, d, 0, 0, 0);
    d = __builtin_amdgcn_mfma_f32_16x16x32_bf16(k1h, aQ1l, d, 0, 0, 0);
    const int4 mvv = *(const int4*)(Mb + s0 + q4 * 4);
    const int mv[4] = {mvv.x, mvv.y, mvv.z, mvv.w};
    float e[4];
    #pragma unroll
    for (int r = 0; r < 4; r++) {
      float x = mv[r] ? d[r] : -1e9f;
      x = fminf(x, 80.f);
      e[r] = __expf(x);
      ls += e[r];
    }
    ppk[ti * 2]     = (unsigned int)f2b(e[0]) | ((unsigned int)f2b(e[1]) << 16);
    ppk[ti * 2 + 1] = (unsigned int)f2b(e[2]) | ((unsigned int)f2b(e[3]) << 16);
  }
  // per-t row sum: reduce across the 4 q4-groups (lanes c16, +16, +32, +48)
  ls += __shfl_xor(ls, 16, 64);
  ls += __shfl_xor(ls, 32, 64);
  if (lane < 16) Lred[w][lane] = ls;
  __syncthreads();
  const float rl = 1.0f / (Lred[0][c16] + Lred[1][c16] + Lred[2][c16] + Lred[3][c16]);

  // ---------------- pass B: full-line P store + PV, no cross-wave sync ----
  f32x4 oacc[4];
  #pragma unroll
  for (int f = 0; f < 4; f++) oacc[f] = (f32x4){0.f, 0.f, 0.f, 0.f};

  float* Pb = Pg + ((size_t)b * Tx + t0) * Sx;
  const int rr = lane >> 3;          // 0..7  (row pair base for the store)
  const int cc = (lane & 7) * 4;     // 0..28 (col within 32-col tile)

  #pragma unroll
  for (int it = 0; it < 16; it++) {
    const int s0 = sBeg + it * 32;
    const int pb = it & 1;           // LDS parity buffer (WAR safety)
    const unsigned int a01 = ppk[it * 4 + 0];
    const unsigned int a23 = ppk[it * 4 + 1];
    const unsigned int b01 = ppk[it * 4 + 2];
    const unsigned int b23 = ppk[it * 4 + 3];
    f32x4 pA, pB;
    pA[0] = b2f((unsigned short)a01) * rl;
    pA[1] = b2f((unsigned short)(a01 >> 16)) * rl;
    pA[2] = b2f((unsigned short)a23) * rl;
    pA[3] = b2f((unsigned short)(a23 >> 16)) * rl;
    pB[0] = b2f((unsigned short)b01) * rl;
    pB[1] = b2f((unsigned short)(b01 >> 16)) * rl;
    pB[2] = b2f((unsigned short)b23) * rl;
    pB[3] = b2f((unsigned short)(b23 >> 16)) * rl;

    // stage the wave's 16x32 P tile in LDS (wave-local, no barrier)
    *(f32x4*)&Pst[w][pb][c16][q4 * 4]      = pA;
    *(f32x4*)&Pst[w][pb][c16][16 + q4 * 4] = pB;

    // PV while the LDS writes drain: A-fragment from normalized e
    // (permuted-Vf contract: k=q4*8+j <-> s = s0 + 4*q4 + (j&3) + 16*(j>>2));
    // B-fragment: one coalesced 1KB chunk per f.
    short8 aP;
    #pragma unroll
    for (int j = 0; j < 4; j++) {
      aP[j]     = (short)f2b(pA[j]);
      aP[4 + j] = (short)f2b(pB[j]);
    }
    const unsigned short* vb = Vfb + (size_t)(w * 16 + it) * 2048 + lane * 8;
    #pragma unroll
    for (int f = 0; f < 4; f++) {
      short8 bV = *(const short8*)(vb + f * 512);
      oacc[f] = __builtin_amdgcn_mfma_f32_16x16x32_bf16(aP, bV, oacc[f], 0, 0, 0);
    }

    // wave-local exchange complete -> re-read row-major, store full lines:
    // 8 lanes cover one row's 32 floats = one full 128B line per row.
    asm volatile("s_waitcnt lgkmcnt(0)" ::: "memory");
    f32x4 v0 = *(const f32x4*)&Pst[w][pb][rr][cc];
    f32x4 v1 = *(const f32x4*)&Pst[w][pb][rr + 8][cc];
    float* p0 = Pb + (size_t)rr * Sx + s0 + cc;
    *(f32x4*)p0 = v0;
    *(f32x4*)(p0 + (size_t)8 * Sx) = v1;
  }

  // PV output: lane holds O[t0 + q4*4 + r][f*16 + c16] (partial over wave's s).
  #pragma unroll
  for (int f = 0; f < 4; f++) {
    #pragma unroll
    for (int r = 0; r < 4; r++) {
      Ored[w][q4 * 4 + r][f * 16 + c16] = oacc[f][r];
    }
  }
  __syncthreads();
  {
    const int t  = tid >> 4;
    const int h4 = (tid & 15) * 4;
    f32x4 a0 = *(const f32x4*)&Ored[0][t][h4];
    f32x4 a1 = *(const f32x4*)&Ored[1][t][h4];
    f32x4 a2 = *(const f32x4*)&Ored[2][t][h4];
    f32x4 a3 = *(const f32x4*)&Ored[3][t][h4];
    f32x4 o;
    #pragma unroll
    for (int j = 0; j < 4; j++) o[j] = a0[j] + a1[j] + a2[j] + a3[j];
    *(f32x4*)(Og + ((size_t)b * Tx + t0 + t) * Hx + h4) = o;
  }
}

// ---------------- slow attention (no-workspace fallback, verbatim) ----------------
__device__ __forceinline__ f32x4 qk_tile(const float* __restrict__ kp,
    short8 aQ0h, short8 aQ0l, short8 aQ1h, short8 aQ1l) {
  f32x4 a0 = *(const f32x4*)(kp);
  f32x4 a1 = *(const f32x4*)(kp + 4);
  f32x4 b0 = *(const f32x4*)(kp + 32);
  f32x4 b1 = *(const f32x4*)(kp + 36);
  short8 k0h, k0l, k1h, k1l;
  cvt_hilo(a0, a1, k0h, k0l);
  cvt_hilo(b0, b1, k1h, k1l);
  f32x4 d = {0.f, 0.f, 0.f, 0.f};
  d = __builtin_amdgcn_mfma_f32_16x16x32_bf16(aQ0h, k0h, d, 0, 0, 0);
  d = __builtin_amdgcn_mfma_f32_16x16x32_bf16(aQ1h, k1h, d, 0, 0, 0);
  d = __builtin_amdgcn_mfma_f32_16x16x32_bf16(aQ0h, k0l, d, 0, 0, 0);
  d = __builtin_amdgcn_mfma_f32_16x16x32_bf16(aQ1h, k1l, d, 0, 0, 0);
  d = __builtin_amdgcn_mfma_f32_16x16x32_bf16(aQ0l, k0h, d, 0, 0, 0);
  d = __builtin_amdgcn_mfma_f32_16x16x32_bf16(aQ1l, k1h, d, 0, 0, 0);
  return d;
}

__global__ void __launch_bounds__(256) attn_kernel(
    const float* __restrict__ Q, const float* __restrict__ K,
    const float* __restrict__ V, const int* __restrict__ mask,
    float* __restrict__ Pg, float* __restrict__ Og) {
  const int tid  = threadIdx.x;
  const int lane = tid & 63;
  const int w    = tid >> 6;
  const int c16  = lane & 15;
  const int q4   = lane >> 4;
  const int b    = blockIdx.x & 7;
  const int t0   = (blockIdx.x >> 3) << 4;

  __shared__ __align__(16) unsigned short Vlds[4][64][40];
  __shared__ __align__(16) float Pf[4][16][36];
  __shared__ float Lred[4][16];
  __shared__ float RL[16];
  __shared__ __align__(16) float Ored[4][16][68];

  const float* Qb = Q + ((size_t)b * Tx + t0) * Hx;
  const float* Kb = K + (size_t)b * Sx * Hx;
  const float* Vb = V + (size_t)b * Sx * Hx;
  const int* Mb = mask + (size_t)b * Sx;

  short8 aQ0h, aQ0l, aQ1h, aQ1l;
  {
    const float* qp = Qb + c16 * Hx + q4 * 8;
    f32x4 qa = *(const f32x4*)qp;
    f32x4 qb = *(const f32x4*)(qp + 4);
    f32x4 qc = *(const f32x4*)(qp + 32);
    f32x4 qd = *(const f32x4*)(qp + 36);
    cvt_hilo(qa, qb, aQ0h, aQ0l);
    cvt_hilo(qc, qd, aQ1h, aQ1l);
  }

  const int sBeg = w * (Sx / 4);

  unsigned int ppk[64];
  float ls[4] = {0.f, 0.f, 0.f, 0.f};
  #pragma unroll
  for (int ti = 0; ti < 32; ti++) {
    const int s0 = sBeg + ti * 16;
    f32x4 d = qk_tile(Kb + (size_t)(s0 + c16) * Hx + q4 * 8,
                      aQ0h, aQ0l, aQ1h, aQ1l);
    const int mv = Mb[s0 + c16];
    float e[4];
    #pragma unroll
    for (int r = 0; r < 4; r++) {
      float x = mv ? d[r] : -1e9f;
      x = fminf(x, 80.f);
      e[r] = __expf(x);
      ls[r] += e[r];
    }
    ppk[ti * 2]     = (unsigned int)f2b(e[0]) | ((unsigned int)f2b(e[1]) << 16);
    ppk[ti * 2 + 1] = (unsigned int)f2b(e[2]) | ((unsigned int)f2b(e[3]) << 16);
  }
  #pragma unroll
  for (int r = 0; r < 4; r++) {
    float v = ls[r];
    v += __shfl_xor(v, 1, 64);
    v += __shfl_xor(v, 2, 64);
    v += __shfl_xor(v, 4, 64);
    v += __shfl_xor(v, 8, 64);
    if (c16 == 0) Lred[w][q4 * 4 + r] = v;
  }
  __syncthreads();
  if (tid < 16) {
    float l = Lred[0][tid] + Lred[1][tid] + Lred[2][tid] + Lred[3][tid];
    RL[tid] = 1.0f / l;
  }
  __syncthreads();

  float rl[4];
  #pragma unroll
  for (int r = 0; r < 4; r++) rl[r] = RL[q4 * 4 + r];

  f32x4 oacc[4];
  #pragma unroll
  for (int f = 0; f < 4; f++) oacc[f] = (f32x4){0.f, 0.f, 0.f, 0.f};

  float* Pb = Pg + ((size_t)b * Tx + t0) * Sx;

  #pragma unroll
  for (int it = 0; it < 16; it++) {
    const int s0 = sBeg + it * 32;
    #pragma unroll
    for (int vit = 0; vit < 8; vit++) {
      int chunk = vit * 64 + lane;
      int sl = chunk >> 4;
      int hq = chunk & 15;
      f32x4 vv = *(const f32x4*)(Vb + (size_t)(s0 + sl) * Hx + hq * 4);
      Vlds[w][hq * 4 + 0][sl] = f2b(vv[0]);
      Vlds[w][hq * 4 + 1][sl] = f2b(vv[1]);
      Vlds[w][hq * 4 + 2][sl] = f2b(vv[2]);
      Vlds[w][hq * 4 + 3][sl] = f2b(vv[3]);
    }
    #pragma unroll
    for (int sub = 0; sub < 2; sub++) {
      unsigned int a01 = ppk[it * 4 + sub * 2];
      unsigned int a23 = ppk[it * 4 + sub * 2 + 1];
      Pf[w][q4 * 4 + 0][sub * 16 + c16] = b2f((unsigned short)a01) * rl[0];
      Pf[w][q4 * 4 + 1][sub * 16 + c16] = b2f((unsigned short)(a01 >> 16)) * rl[1];
      Pf[w][q4 * 4 + 2][sub * 16 + c16] = b2f((unsigned short)a23) * rl[2];
      Pf[w][q4 * 4 + 3][sub * 16 + c16] = b2f((unsigned short)(a23 >> 16)) * rl[3];
    }
    __syncthreads();
    {
      const int row = lane >> 2;
      const int ch  = lane & 3;
      f32x4 v0 = *(const f32x4*)&Pf[w][row][ch * 4];
      f32x4 v1 = *(const f32x4*)&Pf[w][row][16 + ch * 4];
      *(f32x4*)(Pb + (size_t)row * Sx + s0 + ch * 4) = v0;
      *(f32x4*)(Pb + (size_t)row * Sx + s0 + 16 + ch * 4) = v1;
    }
    f32x4 pa = *(const f32x4*)&Pf[w][c16][q4 * 8];
    f32x4 pc = *(const f32x4*)&Pf[w][c16][q4 * 8 + 4];
    short8 aP;
    #pragma unroll
    for (int j = 0; j < 4; j++) {
      aP[j]     = (short)f2b(pa[j]);
      aP[4 + j] = (short)f2b(pc[j]);
    }
    #pragma unroll
    for (int f = 0; f < 4; f++) {
      short8 bV = *(const short8*)&Vlds[w][f * 16 + c16][q4 * 8];
      oacc[f] = __builtin_amdgcn_mfma_f32_16x16x32_bf16(aP, bV, oacc[f], 0, 0, 0);
    }
    __syncthreads();
  }

  #pragma unroll
  for (int f = 0; f < 4; f++) {
    #pragma unroll
    for (int r = 0; r < 4; r++) {
      Ored[w][q4 * 4 + r][f * 16 + c16] = oacc[f][r];
    }
  }
  __syncthreads();
  {
    const int t  = tid >> 4;
    const int h4 = (tid & 15) * 4;
    f32x4 a0 = *(const f32x4*)&Ored[0][t][h4];
    f32x4 a1 = *(const f32x4*)&Ored[1][t][h4];
    f32x4 a2 = *(const f32x4*)&Ored[2][t][h4];
    f32x4 a3 = *(const f32x4*)&Ored[3][t][h4];
    f32x4 o;
    #pragma unroll
    for (int j = 0; j < 4; j++) o[j] = a0[j] + a1[j] + a2[j] + a3[j];
    *(f32x4*)(Og + ((size_t)b * Tx + t0 + t) * Hx + h4) = o;
  }
}

extern "C" void kernel_launch(void* const* d_in, const int* in_sizes, int n_in,
                              void* d_out, int out_size, void* d_ws, size_t ws_size,
                              hipStream_t stream) {
  const float* Q = (const float*)d_in[0];
  const float* K = (const float*)d_in[1];
  const float* V = (const float*)d_in[2];
  const int* mask = (const int*)d_in[3];

  float* Og = (float*)d_out;                       // o_attn: 8*2048*64 fp32
  float* Pg = Og + (size_t)Bx * Tx * Hx;           // p_attn: 8*2048*2048 fp32

  const size_t nKV = (size_t)Bx * Sx * Hx;         // 1,048,576 elements
  if (ws_size >= nKV * 6) {                        // 6 MB: Kf (4MB) + Vf (2MB)
    unsigned short* Kf = (unsigned short*)d_ws;    // hi+lo fragment-packed
    unsigned short* Vf = Kf + nKV * 2;             // fragment-packed, permuted
    prep_kernel<<<dim3(512), dim3(256), 0, stream>>>(K, V, Kf, Vf);
    attn_fast_kernel<<<dim3(Bx * (Tx / 16)), dim3(256), 0, stream>>>(
        Q, mask, Kf, Vf, Pg, Og);
  } else {
    attn_kernel<<<dim3(Bx * (Tx / 16)), dim3(256), 0, stream>>>(Q, K, V, mask, Pg, Og);
  }
}

// Round 6
// 166.168 us; speedup vs baseline: 1.5198x; 1.0437x over previous
//
#include <hip/hip_runtime.h>
#include <stdint.h>

#define Bx 8
#define Tx 2048
#define Sx 2048
#define Hx 64

typedef __attribute__((ext_vector_type(4))) float f32x4;
typedef __attribute__((ext_vector_type(8))) short short8;
typedef __attribute__((ext_vector_type(8))) _Float16 half8;
typedef __attribute__((ext_vector_type(4))) unsigned short ushort4v;

// fp32 -> bf16 round-to-nearest-even (finite inputs only)
__device__ __forceinline__ unsigned short f2b(float f) {
  unsigned int u = __builtin_bit_cast(unsigned int, f);
  u = (u + 0x7FFFu + ((u >> 16) & 1u)) >> 16;
  return (unsigned short)u;
}
__device__ __forceinline__ float b2f(unsigned short h) {
  unsigned int u = ((unsigned int)h) << 16;
  return __builtin_bit_cast(float, u);
}
// fp32 -> fp16 bits (RNE via hardware cvt)
__device__ __forceinline__ unsigned short f2h(float f) {
  return __builtin_bit_cast(unsigned short, (_Float16)f);
}

// 8 fp32 -> (hi, lo) bf16x8 (kept for the no-workspace fallback kernel)
__device__ __forceinline__ void cvt_hilo(f32x4 a, f32x4 b, short8& hi, short8& lo) {
  #pragma unroll
  for (int j = 0; j < 4; j++) {
    unsigned short h = f2b(a[j]);
    hi[j] = (short)h;
    lo[j] = (short)f2b(a[j] - b2f(h));
  }
  #pragma unroll
  for (int j = 0; j < 4; j++) {
    unsigned short h = f2b(b[j]);
    hi[4 + j] = (short)h;
    lo[4 + j] = (short)f2b(b[j] - b2f(h));
  }
}

// ---------------- fused prep kernel (fast path only) ----------------
// Blocks 0..255:  K (fp32 [B,S,64]) -> Kf (fp16 single, R6 change), fragment order:
//   per 16-s tile t: 2 chunks [k0|k1], each 512 halfs lane-linear:
//   chunk_c[lane*8+j] = fp16(K[tile*16 + (lane&15)][(lane>>4)*8 + j + 32*c])
//   -> attn wave loads each chunk as ONE fully-coalesced 1KB dwordx4 load.
//   fp16 (11-bit mantissa) replaces the bf16 hi/lo pair: score err ~5e-3 typ,
//   comparable to the already-tolerated bf16 rounding of P (rel 2^-9).
// Blocks 256..511: V (fp32 [B,S,64]) -> Vf (bf16, UNCHANGED), fragment order
//   with the per-32 s-permutation s(k)=4*(k>>3)+(k&3)+16*((k>>2)&1) baked in:
//   chunk_f[lane*8+j] = bf16(V[m*32 + 4*q4+(j&3)+16*(j>>2)][f*16 + c16])
__global__ void __launch_bounds__(256) prep_kernel(
    const float* __restrict__ K, const float* __restrict__ V,
    unsigned short* __restrict__ Kf, unsigned short* __restrict__ Vf) {
  const int bid = blockIdx.x;
  if (bid < 256) {
    const int b  = bid >> 5;              // 32 s-blocks of 64 per batch
    const int s0 = (bid & 31) << 6;
    __shared__ __align__(16) unsigned short hT[64][68];   // fp16 bits [s][h]
    const float* Kb = K + ((size_t)b * Sx + s0) * Hx;
    #pragma unroll
    for (int r = 0; r < 2; r++) {
      int idx = r * 2048 + threadIdx.x * 8;    // element in 64x64 tile
      int sl = idx >> 6;
      int h0 = idx & 63;
      f32x4 a = *(const f32x4*)(Kb + (size_t)sl * Hx + h0);
      f32x4 c = *(const f32x4*)(Kb + (size_t)sl * Hx + h0 + 4);
      #pragma unroll
      for (int j = 0; j < 4; j++) hT[sl][h0 + j] = f2h(a[j]);
      #pragma unroll
      for (int j = 0; j < 4; j++) hT[sl][h0 + 4 + j] = f2h(c[j]);
    }
    __syncthreads();
    // output: 4 local tiles x 2 chunks x 64 lanes x 16B = 8KB
    unsigned short* out = Kf + ((size_t)b * 128 + (s0 >> 4)) * 1024;
    #pragma unroll
    for (int r = 0; r < 2; r++) {
      int id    = r * 256 + threadIdx.x;  // 0..511 chunk-writes
      int tl    = id >> 7;                // local tile 0..3
      int chunk = (id >> 6) & 1;          // 0:k=0..31  1:k=32..63
      int lane  = id & 63;
      int c16 = lane & 15, q4 = lane >> 4;
      int row = tl * 16 + c16;
      int col = q4 * 8 + chunk * 32;
      ushort4v x0 = *(const ushort4v*)&hT[row][col];
      ushort4v x1 = *(const ushort4v*)&hT[row][col + 4];
      unsigned short* dst = out + ((size_t)tl * 2 + chunk) * 512 + lane * 8;
      *(ushort4v*)dst = x0;
      *(ushort4v*)(dst + 4) = x1;
    }
  } else {
    const int vb = bid - 256;
    const int b  = vb >> 5;
    const int s0 = (vb & 31) << 6;
    __shared__ __align__(16) unsigned short tile[64][72];   // [h][s_local]
    const float* Vb = V + ((size_t)b * Sx + s0) * Hx;
    #pragma unroll
    for (int r = 0; r < 4; r++) {
      int flat = r * 1024 + threadIdx.x * 4;
      int sl = flat >> 6, h = flat & 63;
      f32x4 v = *(const f32x4*)(Vb + (size_t)sl * Hx + h);
      tile[h + 0][sl] = f2b(v[0]);
      tile[h + 1][sl] = f2b(v[1]);
      tile[h + 2][sl] = f2b(v[2]);
      tile[h + 3][sl] = f2b(v[3]);
    }
    __syncthreads();
    unsigned short* out = Vf + ((size_t)b * 64 + (s0 >> 5)) * 2048;
    #pragma unroll
    for (int r = 0; r < 2; r++) {
      int id   = r * 256 + threadIdx.x;   // 0..511 chunk-writes
      int ml   = id >> 8;                 // local 32-s block 0..1
      int f    = (id >> 6) & 3;
      int lane = id & 63;
      int c16 = lane & 15, q4 = lane >> 4;
      int h = f * 16 + c16;
      int sb = ml * 32 + q4 * 4;
      ushort4v lo4 = *(const ushort4v*)&tile[h][sb];        // j=0..3: s'=4q4+j
      ushort4v hi4 = *(const ushort4v*)&tile[h][sb + 16];   // j=4..7: s'=16+4q4+(j-4)
      short8 o;
      #pragma unroll
      for (int j = 0; j < 4; j++) {
        o[j]     = (short)lo4[j];
        o[4 + j] = (short)hi4[j];
      }
      *(short8*)(out + ((size_t)ml * 4 + f) * 512 + lane * 8) = o;
    }
  }
}

// ---------------- fast attention (fragment-packed K fp16 / V bf16) ----------------
// R5 structure; QK^T now fp16-single: 2 coalesced 1KB loads + 2 MFMA per 16-s
// tile (was 4 loads + 6 MFMA with bf16 hi/lo). Halves per-XCD L2 K traffic and
// pass-A issue count. PV path and P packing byte-identical to R5.
__global__ void __launch_bounds__(256) attn_fast_kernel(
    const float* __restrict__ Q, const int* __restrict__ mask,
    const unsigned short* __restrict__ Kf, const unsigned short* __restrict__ Vf,
    float* __restrict__ Pg, float* __restrict__ Og) {
  const int tid  = threadIdx.x;
  const int lane = tid & 63;
  const int w    = tid >> 6;
  const int c16  = lane & 15;
  const int q4   = lane >> 4;
  const int b    = blockIdx.x & 7;          // XCD-affinity: batch <-> XCD
  const int t0   = (blockIdx.x >> 3) << 4;

  __shared__ float Lred[4][16];
  __shared__ __align__(16) float Ored[4][16][68];
  __shared__ __align__(16) float Pst[4][2][16][36];   // wave-local P staging

  const float* Qb = Q + ((size_t)b * Tx + t0) * Hx;
  const unsigned short* Kfb = Kf + (size_t)b * 128 * 1024;
  const unsigned short* Vfb = Vf + (size_t)b * 64 * 2048;
  const int* Mb = mask + (size_t)b * Sx;

  // Q fp16 fragments: B[k=q4*8+j][n=c16] (+32)
  half8 aQ0, aQ1;
  {
    const float* qp = Qb + c16 * Hx + q4 * 8;
    f32x4 qa = *(const f32x4*)qp;
    f32x4 qb = *(const f32x4*)(qp + 4);
    f32x4 qc = *(const f32x4*)(qp + 32);
    f32x4 qd = *(const f32x4*)(qp + 36);
    #pragma unroll
    for (int j = 0; j < 4; j++) {
      aQ0[j]     = (_Float16)qa[j];
      aQ0[4 + j] = (_Float16)qb[j];
      aQ1[j]     = (_Float16)qc[j];
      aQ1[4 + j] = (_Float16)qd[j];
    }
  }

  const int sBeg = w * (Sx / 4);            // 512 s per wave

  // ---------------- pass A: l = sum exp(score), e cached in ppk ----------
  // Swapped operands: lane holds P[t0+c16][s0 + 4*q4 + r], r=0..3.
  unsigned int ppk[64];
  float ls = 0.f;
  #pragma unroll
  for (int ti = 0; ti < 32; ti++) {
    const int s0 = sBeg + ti * 16;
    const unsigned short* kb = Kfb + (size_t)(w * 32 + ti) * 1024 + lane * 8;
    half8 k0 = __builtin_bit_cast(half8, *(const short8*)(kb));
    half8 k1 = __builtin_bit_cast(half8, *(const short8*)(kb + 512));
    f32x4 d = {0.f, 0.f, 0.f, 0.f};
    d = __builtin_amdgcn_mfma_f32_16x16x32_f16(k0, aQ0, d, 0, 0, 0);
    d = __builtin_amdgcn_mfma_f32_16x16x32_f16(k1, aQ1, d, 0, 0, 0);
    const int4 mvv = *(const int4*)(Mb + s0 + q4 * 4);
    const int mv[4] = {mvv.x, mvv.y, mvv.z, mvv.w};
    float e[4];
    #pragma unroll
    for (int r = 0; r < 4; r++) {
      float x = mv[r] ? d[r] : -1e9f;
      x = fminf(x, 80.f);
      e[r] = __expf(x);
      ls += e[r];
    }
    ppk[ti * 2]     = (unsigned int)f2b(e[0]) | ((unsigned int)f2b(e[1]) << 16);
    ppk[ti * 2 + 1] = (unsigned int)f2b(e[2]) | ((unsigned int)f2b(e[3]) << 16);
  }
  // per-t row sum: reduce across the 4 q4-groups (lanes c16, +16, +32, +48)
  ls += __shfl_xor(ls, 16, 64);
  ls += __shfl_xor(ls, 32, 64);
  if (lane < 16) Lred[w][lane] = ls;
  __syncthreads();
  const float rl = 1.0f / (Lred[0][c16] + Lred[1][c16] + Lred[2][c16] + Lred[3][c16]);

  // ---------------- pass B: full-line P store + PV, no cross-wave sync ----
  f32x4 oacc[4];
  #pragma unroll
  for (int f = 0; f < 4; f++) oacc[f] = (f32x4){0.f, 0.f, 0.f, 0.f};

  float* Pb = Pg + ((size_t)b * Tx + t0) * Sx;
  const int rr = lane >> 3;          // 0..7  (row pair base for the store)
  const int cc = (lane & 7) * 4;     // 0..28 (col within 32-col tile)

  #pragma unroll
  for (int it = 0; it < 16; it++) {
    const int s0 = sBeg + it * 32;
    const int pb = it & 1;           // LDS parity buffer (WAR safety)
    const unsigned int a01 = ppk[it * 4 + 0];
    const unsigned int a23 = ppk[it * 4 + 1];
    const unsigned int b01 = ppk[it * 4 + 2];
    const unsigned int b23 = ppk[it * 4 + 3];
    f32x4 pA, pB;
    pA[0] = b2f((unsigned short)a01) * rl;
    pA[1] = b2f((unsigned short)(a01 >> 16)) * rl;
    pA[2] = b2f((unsigned short)a23) * rl;
    pA[3] = b2f((unsigned short)(a23 >> 16)) * rl;
    pB[0] = b2f((unsigned short)b01) * rl;
    pB[1] = b2f((unsigned short)(b01 >> 16)) * rl;
    pB[2] = b2f((unsigned short)b23) * rl;
    pB[3] = b2f((unsigned short)(b23 >> 16)) * rl;

    // stage the wave's 16x32 P tile in LDS (wave-local, no barrier)
    *(f32x4*)&Pst[w][pb][c16][q4 * 4]      = pA;
    *(f32x4*)&Pst[w][pb][c16][16 + q4 * 4] = pB;

    // PV while the LDS writes drain: A-fragment from normalized e
    // (permuted-Vf contract: k=q4*8+j <-> s = s0 + 4*q4 + (j&3) + 16*(j>>2));
    // B-fragment: one coalesced 1KB chunk per f.
    short8 aP;
    #pragma unroll
    for (int j = 0; j < 4; j++) {
      aP[j]     = (short)f2b(pA[j]);
      aP[4 + j] = (short)f2b(pB[j]);
    }
    const unsigned short* vb = Vfb + (size_t)(w * 16 + it) * 2048 + lane * 8;
    #pragma unroll
    for (int f = 0; f < 4; f++) {
      short8 bV = *(const short8*)(vb + f * 512);
      oacc[f] = __builtin_amdgcn_mfma_f32_16x16x32_bf16(aP, bV, oacc[f], 0, 0, 0);
    }

    // wave-local exchange complete -> re-read row-major, store full lines:
    // 8 lanes cover one row's 32 floats = one full 128B line per row.
    asm volatile("s_waitcnt lgkmcnt(0)" ::: "memory");
    f32x4 v0 = *(const f32x4*)&Pst[w][pb][rr][cc];
    f32x4 v1 = *(const f32x4*)&Pst[w][pb][rr + 8][cc];
    float* p0 = Pb + (size_t)rr * Sx + s0 + cc;
    *(f32x4*)p0 = v0;
    *(f32x4*)(p0 + (size_t)8 * Sx) = v1;
  }

  // PV output: lane holds O[t0 + q4*4 + r][f*16 + c16] (partial over wave's s).
  #pragma unroll
  for (int f = 0; f < 4; f++) {
    #pragma unroll
    for (int r = 0; r < 4; r++) {
      Ored[w][q4 * 4 + r][f * 16 + c16] = oacc[f][r];
    }
  }
  __syncthreads();
  {
    const int t  = tid >> 4;
    const int h4 = (tid & 15) * 4;
    f32x4 a0 = *(const f32x4*)&Ored[0][t][h4];
    f32x4 a1 = *(const f32x4*)&Ored[1][t][h4];
    f32x4 a2 = *(const f32x4*)&Ored[2][t][h4];
    f32x4 a3 = *(const f32x4*)&Ored[3][t][h4];
    f32x4 o;
    #pragma unroll
    for (int j = 0; j < 4; j++) o[j] = a0[j] + a1[j] + a2[j] + a3[j];
    *(f32x4*)(Og + ((size_t)b * Tx + t0 + t) * Hx + h4) = o;
  }
}

// ---------------- slow attention (no-workspace fallback, verbatim) ----------------
__device__ __forceinline__ f32x4 qk_tile(const float* __restrict__ kp,
    short8 aQ0h, short8 aQ0l, short8 aQ1h, short8 aQ1l) {
  f32x4 a0 = *(const f32x4*)(kp);
  f32x4 a1 = *(const f32x4*)(kp + 4);
  f32x4 b0 = *(const f32x4*)(kp + 32);
  f32x4 b1 = *(const f32x4*)(kp + 36);
  short8 k0h, k0l, k1h, k1l;
  cvt_hilo(a0, a1, k0h, k0l);
  cvt_hilo(b0, b1, k1h, k1l);
  f32x4 d = {0.f, 0.f, 0.f, 0.f};
  d = __builtin_amdgcn_mfma_f32_16x16x32_bf16(aQ0h, k0h, d, 0, 0, 0);
  d = __builtin_amdgcn_mfma_f32_16x16x32_bf16(aQ1h, k1h, d, 0, 0, 0);
  d = __builtin_amdgcn_mfma_f32_16x16x32_bf16(aQ0h, k0l, d, 0, 0, 0);
  d = __builtin_amdgcn_mfma_f32_16x16x32_bf16(aQ1h, k1l, d, 0, 0, 0);
  d = __builtin_amdgcn_mfma_f32_16x16x32_bf16(aQ0l, k0h, d, 0, 0, 0);
  d = __builtin_amdgcn_mfma_f32_16x16x32_bf16(aQ1l, k1h, d, 0, 0, 0);
  return d;
}

__global__ void __launch_bounds__(256) attn_kernel(
    const float* __restrict__ Q, const float* __restrict__ K,
    const float* __restrict__ V, const int* __restrict__ mask,
    float* __restrict__ Pg, float* __restrict__ Og) {
  const int tid  = threadIdx.x;
  const int lane = tid & 63;
  const int w    = tid >> 6;
  const int c16  = lane & 15;
  const int q4   = lane >> 4;
  const int b    = blockIdx.x & 7;
  const int t0   = (blockIdx.x >> 3) << 4;

  __shared__ __align__(16) unsigned short Vlds[4][64][40];
  __shared__ __align__(16) float Pf[4][16][36];
  __shared__ float Lred[4][16];
  __shared__ float RL[16];
  __shared__ __align__(16) float Ored[4][16][68];

  const float* Qb = Q + ((size_t)b * Tx + t0) * Hx;
  const float* Kb = K + (size_t)b * Sx * Hx;
  const float* Vb = V + (size_t)b * Sx * Hx;
  const int* Mb = mask + (size_t)b * Sx;

  short8 aQ0h, aQ0l, aQ1h, aQ1l;
  {
    const float* qp = Qb + c16 * Hx + q4 * 8;
    f32x4 qa = *(const f32x4*)qp;
    f32x4 qb = *(const f32x4*)(qp + 4);
    f32x4 qc = *(const f32x4*)(qp + 32);
    f32x4 qd = *(const f32x4*)(qp + 36);
    cvt_hilo(qa, qb, aQ0h, aQ0l);
    cvt_hilo(qc, qd, aQ1h, aQ1l);
  }

  const int sBeg = w * (Sx / 4);

  unsigned int ppk[64];
  float ls[4] = {0.f, 0.f, 0.f, 0.f};
  #pragma unroll
  for (int ti = 0; ti < 32; ti++) {
    const int s0 = sBeg + ti * 16;
    f32x4 d = qk_tile(Kb + (size_t)(s0 + c16) * Hx + q4 * 8,
                      aQ0h, aQ0l, aQ1h, aQ1l);
    const int mv = Mb[s0 + c16];
    float e[4];
    #pragma unroll
    for (int r = 0; r < 4; r++) {
      float x = mv ? d[r] : -1e9f;
      x = fminf(x, 80.f);
      e[r] = __expf(x);
      ls[r] += e[r];
    }
    ppk[ti * 2]     = (unsigned int)f2b(e[0]) | ((unsigned int)f2b(e[1]) << 16);
    ppk[ti * 2 + 1] = (unsigned int)f2b(e[2]) | ((unsigned int)f2b(e[3]) << 16);
  }
  #pragma unroll
  for (int r = 0; r < 4; r++) {
    float v = ls[r];
    v += __shfl_xor(v, 1, 64);
    v += __shfl_xor(v, 2, 64);
    v += __shfl_xor(v, 4, 64);
    v += __shfl_xor(v, 8, 64);
    if (c16 == 0) Lred[w][q4 * 4 + r] = v;
  }
  __syncthreads();
  if (tid < 16) {
    float l = Lred[0][tid] + Lred[1][tid] + Lred[2][tid] + Lred[3][tid];
    RL[tid] = 1.0f / l;
  }
  __syncthreads();

  float rl[4];
  #pragma unroll
  for (int r = 0; r < 4; r++) rl[r] = RL[q4 * 4 + r];

  f32x4 oacc[4];
  #pragma unroll
  for (int f = 0; f < 4; f++) oacc[f] = (f32x4){0.f, 0.f, 0.f, 0.f};

  float* Pb = Pg + ((size_t)b * Tx + t0) * Sx;

  #pragma unroll
  for (int it = 0; it < 16; it++) {
    const int s0 = sBeg + it * 32;
    #pragma unroll
    for (int vit = 0; vit < 8; vit++) {
      int chunk = vit * 64 + lane;
      int sl = chunk >> 4;
      int hq = chunk & 15;
      f32x4 vv = *(const f32x4*)(Vb + (size_t)(s0 + sl) * Hx + hq * 4);
      Vlds[w][hq * 4 + 0][sl] = f2b(vv[0]);
      Vlds[w][hq * 4 + 1][sl] = f2b(vv[1]);
      Vlds[w][hq * 4 + 2][sl] = f2b(vv[2]);
      Vlds[w][hq * 4 + 3][sl] = f2b(vv[3]);
    }
    #pragma unroll
    for (int sub = 0; sub < 2; sub++) {
      unsigned int a01 = ppk[it * 4 + sub * 2];
      unsigned int a23 = ppk[it * 4 + sub * 2 + 1];
      Pf[w][q4 * 4 + 0][sub * 16 + c16] = b2f((unsigned short)a01) * rl[0];
      Pf[w][q4 * 4 + 1][sub * 16 + c16] = b2f((unsigned short)(a01 >> 16)) * rl[1];
      Pf[w][q4 * 4 + 2][sub * 16 + c16] = b2f((unsigned short)a23) * rl[2];
      Pf[w][q4 * 4 + 3][sub * 16 + c16] = b2f((unsigned short)(a23 >> 16)) * rl[3];
    }
    __syncthreads();
    {
      const int row = lane >> 2;
      const int ch  = lane & 3;
      f32x4 v0 = *(const f32x4*)&Pf[w][row][ch * 4];
      f32x4 v1 = *(const f32x4*)&Pf[w][row][16 + ch * 4];
      *(f32x4*)(Pb + (size_t)row * Sx + s0 + ch * 4) = v0;
      *(f32x4*)(Pb + (size_t)row * Sx + s0 + 16 + ch * 4) = v1;
    }
    f32x4 pa = *(const f32x4*)&Pf[w][c16][q4 * 8];
    f32x4 pc = *(const f32x4*)&Pf[w][c16][q4 * 8 + 4];
    short8 aP;
    #pragma unroll
    for (int j = 0; j < 4; j++) {
      aP[j]     = (short)f2b(pa[j]);
      aP[4 + j] = (short)f2b(pc[j]);
    }
    #pragma unroll
    for (int f = 0; f < 4; f++) {
      short8 bV = *(const short8*)&Vlds[w][f * 16 + c16][q4 * 8];
      oacc[f] = __builtin_amdgcn_mfma_f32_16x16x32_bf16(aP, bV, oacc[f], 0, 0, 0);
    }
    __syncthreads();
  }

  #pragma unroll
  for (int f = 0; f < 4; f++) {
    #pragma unroll
    for (int r = 0; r < 4; r++) {
      Ored[w][q4 * 4 + r][f * 16 + c16] = oacc[f][r];
    }
  }
  __syncthreads();
  {
    const int t  = tid >> 4;
    const int h4 = (tid & 15) * 4;
    f32x4 a0 = *(const f32x4*)&Ored[0][t][h4];
    f32x4 a1 = *(const f32x4*)&Ored[1][t][h4];
    f32x4 a2 = *(const f32x4*)&Ored[2][t][h4];
    f32x4 a3 = *(const f32x4*)&Ored[3][t][h4];
    f32x4 o;
    #pragma unroll
    for (int j = 0; j < 4; j++) o[j] = a0[j] + a1[j] + a2[j] + a3[j];
    *(f32x4*)(Og + ((size_t)b * Tx + t0 + t) * Hx + h4) = o;
  }
}

extern "C" void kernel_launch(void* const* d_in, const int* in_sizes, int n_in,
                              void* d_out, int out_size, void* d_ws, size_t ws_size,
                              hipStream_t stream) {
  const float* Q = (const float*)d_in[0];
  const float* K = (const float*)d_in[1];
  const float* V = (const float*)d_in[2];
  const int* mask = (const int*)d_in[3];

  float* Og = (float*)d_out;                       // o_attn: 8*2048*64 fp32
  float* Pg = Og + (size_t)Bx * Tx * Hx;           // p_attn: 8*2048*2048 fp32

  const size_t nKV = (size_t)Bx * Sx * Hx;         // 1,048,576 elements
  if (ws_size >= nKV * 6) {                        // need 4MB: Kf16 2MB + Vf 2MB
    unsigned short* Kf = (unsigned short*)d_ws;    // fp16 fragment-packed K
    unsigned short* Vf = Kf + nKV;                 // bf16 fragment-packed V (permuted)
    prep_kernel<<<dim3(512), dim3(256), 0, stream>>>(K, V, Kf, Vf);
    attn_fast_kernel<<<dim3(Bx * (Tx / 16)), dim3(256), 0, stream>>>(
        Q, mask, Kf, Vf, Pg, Og);
  } else {
    attn_kernel<<<dim3(Bx * (Tx / 16)), dim3(256), 0, stream>>>(Q, K, V, mask, Pg, Og);
  }
}